// Round 2
// baseline (1524.686 us; speedup 1.0000x reference)
//
#include <hip/hip_runtime.h>
#include <hip/hip_bf16.h>

#define TPB 256
constexpr int NB = 32;     // batch
constexpr int NC = 256;    // channels
constexpr int NL = 1024;   // sequence (H*W)
constexpr int BI = 32;     // i-tile rows
constexpr int BJ = 32;     // j-tile cols
constexpr int QP = NC + 4;   // qT row pitch (floats), 16B-aligned rows, conflict pad
constexpr int KP = 128 + 4;  // kT half-tile pitch
constexpr int PP = BI + 4;   // pT pitch (rows j, cols i)

constexpr int OFF_QT = 0;                  // 32*260 = 8320 floats
constexpr int OFF_KT = OFF_QT + BI * QP;   // + 32*132 = 4224
constexpr int OFF_PT = OFF_KT + BJ * KP;   // + 32*36  = 1152
constexpr int OFF_M  = OFF_PT + BJ * PP;
constexpr int OFF_L  = OFF_M + BI;
constexpr int OFF_A  = OFF_L + BI;
constexpr int SMEM_N = OFF_A + BI;         // 13792 floats = 55168 B < 64 KB

__global__ __launch_bounds__(TPB)
void att_fwd(const float* __restrict__ q,
             const float* __restrict__ kk,
             const float* __restrict__ v,
             const float* __restrict__ sd,
             const float* __restrict__ bt,
             const int* __restrict__ ri,
             float* __restrict__ out)
{
    __shared__ __align__(16) float smem[SMEM_N];
    float* qT   = smem + OFF_QT;   // qT[i][c] fp32
    float* kT   = smem + OFF_KT;   // kT[j][c-half] fp32
    float* pT   = smem + OFF_PT;   // pT[j][i] scores -> probabilities
    float* mrow = smem + OFF_M;
    float* lrow = smem + OFF_L;
    float* arow = smem + OFF_A;

    const int tid = threadIdx.x;
    const int ib  = blockIdx.x;
    const int b   = blockIdx.y;
    const int i0  = ib * BI;

    // ---- stage Q block transposed: qT[i][c] = q[b][c][i0+i] ----
    {
        const float* qb = q + (size_t)b * NC * NL + i0;
        for (int t = tid; t < NC * BI; t += TPB) {
            int i = t & (BI - 1), c = t >> 5;
            qT[i * QP + c] = qb[(size_t)c * NL + i];
        }
    }
    if (tid < BI) { mrow[tid] = -1e30f; lrow[tid] = 0.0f; }

    float accV[BI], accSD[BI];
    #pragma unroll
    for (int i = 0; i < BI; ++i) { accV[i] = 0.0f; accSD[i] = 0.0f; }

    const int tx = tid & 15;       // j-pair selector
    const int ty = tid >> 4;       // i-pair selector
    const int iA = 2 * ty, iB = 2 * ty + 1;
    const int jA = 2 * tx, jB = 2 * tx + 1;

    const float* vrow = v  + ((size_t)b * NC + tid) * NL;  // thread owns channel c=tid
    const float* srow = sd + ((size_t)b * NC + tid) * NL;

    for (int jt = 0; jt < NL / BJ; ++jt) {
        const int j0 = jt * BJ;
        float s00 = 0.f, s01 = 0.f, s10 = 0.f, s11 = 0.f;

        // ---- scores: QtK over c in two 128-channel halves (kT restaged) ----
        for (int ch = 0; ch < 2; ++ch) {
            __syncthreads();   // previous consumers of kT/pT done
            const float* kb = kk + ((size_t)b * NC + 128 * ch) * NL + j0;
            for (int t = tid; t < 128 * BJ; t += TPB) {
                int j = t & (BJ - 1), c = t >> 5;
                kT[j * KP + c] = kb[(size_t)c * NL + j];
            }
            __syncthreads();

            const float4* q0 = (const float4*)(qT + iA * QP + 128 * ch);
            const float4* q1 = (const float4*)(qT + iB * QP + 128 * ch);
            const float4* k0 = (const float4*)(kT + jA * KP);
            const float4* k1 = (const float4*)(kT + jB * KP);
            #pragma unroll 8
            for (int c4 = 0; c4 < 32; ++c4) {
                float4 qa = q0[c4], qb4 = q1[c4];
                float4 ka = k0[c4], kb4 = k1[c4];
                s00 += qa.x * ka.x  + qa.y * ka.y  + qa.z * ka.z  + qa.w * ka.w;
                s01 += qa.x * kb4.x + qa.y * kb4.y + qa.z * kb4.z + qa.w * kb4.w;
                s10 += qb4.x * ka.x + qb4.y * ka.y + qb4.z * ka.z + qb4.w * ka.w;
                s11 += qb4.x * kb4.x + qb4.y * kb4.y + qb4.z * kb4.z + qb4.w * kb4.w;
            }
        }

        // ---- add relative-position bias, write pT[j][i] ----
        {
            const int* r0 = ri + (size_t)(i0 + iA) * NL + j0;
            const int* r1 = ri + (size_t)(i0 + iB) * NL + j0;
            pT[jA * PP + iA] = s00 + bt[r0[jA]];
            pT[jB * PP + iA] = s01 + bt[r0[jB]];
            pT[jA * PP + iB] = s10 + bt[r1[jA]];
            pT[jB * PP + iB] = s11 + bt[r1[jB]];
        }
        __syncthreads();

        // ---- online softmax state update: 8 threads per row, shfl reduce ----
        {
            const int i = tid >> 3;      // row 0..31
            const int s = tid & 7;       // slot 0..7, 4 j's each (same wave per row)
            float p[4];
            float lm = -1e30f;
            #pragma unroll
            for (int jj = 0; jj < 4; ++jj) {
                p[jj] = pT[(s * 4 + jj) * PP + i];
                lm = fmaxf(lm, p[jj]);
            }
            #pragma unroll
            for (int d = 1; d < 8; d <<= 1)
                lm = fmaxf(lm, __shfl_xor(lm, d));
            const float mo = mrow[i];          // read by all 8 slots (lockstep, same wave)
            const float tm = fmaxf(lm, mo);
            float sum = 0.f;
            #pragma unroll
            for (int jj = 0; jj < 4; ++jj) {
                float e = __expf(p[jj] - tm);
                pT[(s * 4 + jj) * PP + i] = e;
                sum += e;
            }
            #pragma unroll
            for (int d = 1; d < 8; d <<= 1)
                sum += __shfl_xor(sum, d);
            if (s == 0) {
                float al = __expf(mo - tm);
                arow[i] = al;
                lrow[i] = lrow[i] * al + sum;
                mrow[i] = tm;
            }
        }
        __syncthreads();

        // ---- rescale accumulators, then acc += P * v / P * std ----
        #pragma unroll
        for (int i = 0; i < BI; ++i) {
            float a = arow[i];
            accV[i]  *= a;
            accSD[i] *= a;
        }
        const float4* vp = (const float4*)(vrow + j0);
        const float4* sp = (const float4*)(srow + j0);
        #pragma unroll 2
        for (int j4 = 0; j4 < BJ / 4; ++j4) {
            float4 vv = vp[j4], ss = sp[j4];
            float pv[4] = { vv.x, vv.y, vv.z, vv.w };
            float ps[4] = { ss.x, ss.y, ss.z, ss.w };
            #pragma unroll
            for (int jj = 0; jj < 4; ++jj) {
                const float4* pr = (const float4*)(pT + (4 * j4 + jj) * PP);
                #pragma unroll
                for (int i4 = 0; i4 < BI / 4; ++i4) {
                    float4 p4 = pr[i4];   // broadcast read (all lanes same addr)
                    accV[4*i4+0] += p4.x * pv[jj];  accSD[4*i4+0] += p4.x * ps[jj];
                    accV[4*i4+1] += p4.y * pv[jj];  accSD[4*i4+1] += p4.y * ps[jj];
                    accV[4*i4+2] += p4.z * pv[jj];  accSD[4*i4+2] += p4.z * ps[jj];
                    accV[4*i4+3] += p4.w * pv[jj];  accSD[4*i4+3] += p4.w * ps[jj];
                }
            }
        }
    }

    // ---- epilogue: normalize, transpose via LDS (reuse qT/kT region), coalesced store ----
    __syncthreads();
    float* scr = smem;   // 256*33 = 8448 floats, overlaps dead qT/kT
    #pragma unroll
    for (int i = 0; i < BI; ++i) scr[tid * 33 + i] = accV[i] / lrow[i];
    __syncthreads();
    {
        float* ob = out + (size_t)b * NC * NL + i0;
        for (int t = tid; t < NC * BI; t += TPB) {
            int i = t & 31, c = t >> 5;
            ob[(size_t)c * NL + i] = scr[c * 33 + i];
        }
    }
    __syncthreads();
    #pragma unroll
    for (int i = 0; i < BI; ++i) scr[tid * 33 + i] = accSD[i] / lrow[i];
    __syncthreads();
    {
        float* ob = out + (size_t)NB * NC * NL + (size_t)b * NC * NL + i0;
        for (int t = tid; t < NC * BI; t += TPB) {
            int i = t & 31, c = t >> 5;
            ob[(size_t)c * NL + i] = scr[c * 33 + i];
        }
    }
}

extern "C" void kernel_launch(void* const* d_in, const int* in_sizes, int n_in,
                              void* d_out, int out_size, void* d_ws, size_t ws_size,
                              hipStream_t stream)
{
    (void)in_sizes; (void)n_in; (void)d_ws; (void)ws_size; (void)out_size;
    const float* q  = (const float*)d_in[0];
    const float* k  = (const float*)d_in[1];
    const float* v  = (const float*)d_in[2];
    const float* s  = (const float*)d_in[3];
    const float* bt = (const float*)d_in[4];
    const int*   ri = (const int*)d_in[5];
    dim3 grid(NL / BI, NB);
    att_fwd<<<grid, dim3(TPB), 0, stream>>>(q, k, v, s, bt, ri, (float*)d_out);
}

// Round 3
// 563.519 us; speedup vs baseline: 2.7057x; 2.7057x over previous
//
#include <hip/hip_runtime.h>
#include <hip/hip_bf16.h>

typedef _Float16 half8  __attribute__((ext_vector_type(8)));
typedef float    floatx16 __attribute__((ext_vector_type(16)));

constexpr int NB = 32;     // batch
constexpr int NC = 256;    // channels
constexpr int NL = 1024;   // sequence
constexpr int MI = 32;     // i-rows per block
constexpr int BJ = 64;     // j-tile
constexpr int NIT = NL / BJ;   // 16 j-iterations

// LDS byte offsets
constexpr int OFF_K    = 0;                         // kFrag fp16, frag-order: 16 ks * 2 jt * 64 lane * 8 = 16384 f16 = 32768 B
constexpr int OFF_PS   = 32768;                     // pS fp32 [2][32][65] = 16640 B
constexpr int PS_PITCH = 65;
constexpr int PS_KH    = 32 * PS_PITCH;             // 2080 floats per kh partial
constexpr int OFF_PB   = OFF_PS + 2 * PS_KH * 4;    // 49408: pB fp16 frag-order [4 ksj][64][8] = 4096 B
constexpr int OFF_ROWS = OFF_PB + 4096;             // 53504: mrow/lrow/arow 3*32*4 = 384 B
constexpr int SMEM_B   = OFF_ROWS + 384;            // 53888 B

__global__ __launch_bounds__(256, 2)
void att_mfma(const float* __restrict__ q,
              const float* __restrict__ kk,
              const float* __restrict__ v,
              const float* __restrict__ sd,
              const float* __restrict__ bt,
              const int* __restrict__ ri,
              float* __restrict__ out)
{
    __shared__ __align__(16) char smem[SMEM_B];
    _Float16* kF   = (_Float16*)(smem + OFF_K);
    float*    pS   = (float*)(smem + OFF_PS);
    _Float16* pB   = (_Float16*)(smem + OFF_PB);
    float*    mrow = (float*)(smem + OFF_ROWS);
    float*    lrow = mrow + 32;
    float*    arow = mrow + 64;

    const int tid  = threadIdx.x;
    const int lane = tid & 63;
    const int wv   = tid >> 6;
    const int kh   = wv & 1;       // c-half for scores
    const int jt   = wv >> 1;      // j-half (32) for scores

    // XCD-locality swizzle: the 32 i-blocks of one batch land on one XCD (bid%8 heuristic).
    const int bid = blockIdx.x;
    const int b   = (bid & 7) + ((bid >> 8) << 3);
    const int ib  = (bid >> 3) & 31;
    const int i0  = ib * MI;

    // ---- Q A-fragments (hi/lo fp16) in registers: A[m=lane&31][k=(lane>>5)*8+t] ----
    half8 qhi[8], qlo[8];
    {
        const int m   = lane & 31;
        const int kq8 = (lane >> 5) * 8;
        const float* qb = q + (size_t)b * NC * NL + i0 + m;
        #pragma unroll
        for (int kk2 = 0; kk2 < 8; ++kk2) {
            const int c0 = (kh * 8 + kk2) * 16 + kq8;
            #pragma unroll
            for (int t = 0; t < 8; ++t) {
                float x = qb[(size_t)(c0 + t) * NL];
                _Float16 h = (_Float16)x;
                qhi[kk2][t] = h;
                qlo[kk2][t] = (_Float16)(x - (float)h);
            }
        }
    }
    if (tid < 32) { mrow[tid] = -1e30f; lrow[tid] = 0.0f; }

    floatx16 accV[2], accSD[2];
    #pragma unroll
    for (int d = 0; d < 2; ++d)
        #pragma unroll
        for (int r = 0; r < 16; ++r) { accV[d][r] = 0.f; accSD[d][r] = 0.f; }

    const float* kbase = kk + (size_t)b * NC * NL;

    // ---- stage K tile for iter 0 ----
    {
        const float* kb = kbase;   // j0 = 0
        #pragma unroll 2
        for (int r = 0; r < 8; ++r) {
            int tk = tid + r * 256;
            int c0 = (tk >> 4) * 2;
            int jq = tk & 15;
            const float* row0 = kb + (size_t)c0 * NL + jq * 4;
            float4 a4 = *(const float4*)row0;
            float4 b4 = *(const float4*)(row0 + NL);
            int ks = c0 >> 4, t = c0 & 7, l5 = (c0 >> 3) & 1;
            #pragma unroll
            for (int x = 0; x < 4; ++x) {
                int j = jq * 4 + x;
                int idx = ((ks * 2 + (j >> 5)) * 64 + l5 * 32 + (j & 31)) * 8 + t;
                union { _Float16 h[2]; unsigned int u; } p;
                p.h[0] = (_Float16)((&a4.x)[x]);
                p.h[1] = (_Float16)((&b4.x)[x]);
                *(unsigned int*)(kF + idx) = p.u;
            }
        }
    }
    __syncthreads();

    for (int it = 0; it < NIT; ++it) {
        const int j0g = it * BJ;

        // ---- scores: S(partial over this wave's c-half) = Qhi*K + Qlo*K ----
        floatx16 S;
        #pragma unroll
        for (int r = 0; r < 16; ++r) S[r] = 0.f;
        #pragma unroll
        for (int kk2 = 0; kk2 < 8; ++kk2) {
            const int ks = kh * 8 + kk2;
            half8 bf = *(const half8*)(kF + ((ks * 2 + jt) * 64 + lane) * 8);
            S = __builtin_amdgcn_mfma_f32_32x32x16_f16(qhi[kk2], bf, S, 0, 0, 0);
            S = __builtin_amdgcn_mfma_f32_32x32x16_f16(qlo[kk2], bf, S, 0, 0, 0);
        }
        {
            const int colj = jt * 32 + (lane & 31);
            float* ps = pS + kh * PS_KH + colj;
            #pragma unroll
            for (int r = 0; r < 16; ++r) {
                int row = (r & 3) + 8 * (r >> 2) + 4 * (lane >> 5);
                ps[row * PS_PITCH] = S[r];
            }
        }
        __syncthreads();   // pS ready; kFrag reads of iter `it` done

        // ---- stage K for next iter (kFrag free now) ----
        if (it + 1 < NIT) {
            const float* kb = kbase + j0g + BJ;
            #pragma unroll 2
            for (int r = 0; r < 8; ++r) {
                int tk = tid + r * 256;
                int c0 = (tk >> 4) * 2;
                int jq = tk & 15;
                const float* row0 = kb + (size_t)c0 * NL + jq * 4;
                float4 a4 = *(const float4*)row0;
                float4 b4 = *(const float4*)(row0 + NL);
                int ks = c0 >> 4, t = c0 & 7, l5 = (c0 >> 3) & 1;
                #pragma unroll
                for (int x = 0; x < 4; ++x) {
                    int j = jq * 4 + x;
                    int idx = ((ks * 2 + (j >> 5)) * 64 + l5 * 32 + (j & 31)) * 8 + t;
                    union { _Float16 h[2]; unsigned int u; } p;
                    p.h[0] = (_Float16)((&a4.x)[x]);
                    p.h[1] = (_Float16)((&b4.x)[x]);
                    *(unsigned int*)(kF + idx) = p.u;
                }
            }
        }

        // ---- softmax (online): 8 threads per row i, 8 cols each ----
        {
            const int i = tid >> 3, s = tid & 7;
            const int* rip = ri + (size_t)(i0 + i) * NL + j0g + s * 8;
            const float* ps0 = pS + i * PS_PITCH + s * 8;
            float sc[8];
            #pragma unroll
            for (int jj = 0; jj < 8; ++jj)
                sc[jj] = ps0[jj] + ps0[PS_KH + jj] + bt[rip[jj]];
            float lm = sc[0];
            #pragma unroll
            for (int jj = 1; jj < 8; ++jj) lm = fmaxf(lm, sc[jj]);
            lm = fmaxf(lm, __shfl_xor(lm, 1));
            lm = fmaxf(lm, __shfl_xor(lm, 2));
            lm = fmaxf(lm, __shfl_xor(lm, 4));
            const float mo = mrow[i];
            const float mn = fmaxf(lm, mo);
            float sum = 0.f;
            half8 ph;
            #pragma unroll
            for (int jj = 0; jj < 8; ++jj) {
                float e = __expf(sc[jj] - mn);
                sum += e;
                ph[jj] = (_Float16)e;
            }
            sum += __shfl_xor(sum, 1);
            sum += __shfl_xor(sum, 2);
            sum += __shfl_xor(sum, 4);
            if (s == 0) {
                float al = __expf(mo - mn);
                arow[i] = al;
                lrow[i] = lrow[i] * al + sum;
                mrow[i] = mn;
            }
            *(half8*)(pB + (s >> 1) * 512 + (s & 1) * 256 + i * 8) = ph;
        }
        __syncthreads();   // pB, arow, kFrag(next) ready

        // ---- PV: out^T[c][i] += v/std frags * P;  D n-dim = i (uniform per lane) ----
        {
            const float al = arow[lane & 31];
            #pragma unroll
            for (int d = 0; d < 2; ++d)
                #pragma unroll
                for (int r = 0; r < 16; ++r) { accV[d][r] *= al; accSD[d][r] *= al; }

            half8 pb[4];
            #pragma unroll
            for (int ksj = 0; ksj < 4; ++ksj)
                pb[ksj] = *(const half8*)(pB + (ksj * 64 + lane) * 8);

            const int mi  = lane & 31;
            const int kq8 = (lane >> 5) * 8;
            const size_t rowoff = (size_t)b * NC * NL + (size_t)mi * NL + j0g + kq8;
            #pragma unroll
            for (int d = 0; d < 2; ++d) {
                const int ct = wv + d * 4;
                const float* vrow = v  + rowoff + (size_t)(ct * 32) * NL;
                const float* srow = sd + rowoff + (size_t)(ct * 32) * NL;
                #pragma unroll
                for (int ksj = 0; ksj < 4; ++ksj) {
                    float4 x0 = *(const float4*)(vrow + ksj * 16);
                    float4 x1 = *(const float4*)(vrow + ksj * 16 + 4);
                    half8 av;
                    av[0]=(_Float16)x0.x; av[1]=(_Float16)x0.y; av[2]=(_Float16)x0.z; av[3]=(_Float16)x0.w;
                    av[4]=(_Float16)x1.x; av[5]=(_Float16)x1.y; av[6]=(_Float16)x1.z; av[7]=(_Float16)x1.w;
                    accV[d] = __builtin_amdgcn_mfma_f32_32x32x16_f16(av, pb[ksj], accV[d], 0, 0, 0);
                    float4 y0 = *(const float4*)(srow + ksj * 16);
                    float4 y1 = *(const float4*)(srow + ksj * 16 + 4);
                    half8 as;
                    as[0]=(_Float16)y0.x; as[1]=(_Float16)y0.y; as[2]=(_Float16)y0.z; as[3]=(_Float16)y0.w;
                    as[4]=(_Float16)y1.x; as[5]=(_Float16)y1.y; as[6]=(_Float16)y1.z; as[7]=(_Float16)y1.w;
                    accSD[d] = __builtin_amdgcn_mfma_f32_32x32x16_f16(as, pb[ksj], accSD[d], 0, 0, 0);
                }
            }
        }
    }

    // ---- epilogue: scale by 1/l, transpose via LDS scratch, coalesced store ----
    const float linv = 1.0f / lrow[lane & 31];
    float* scr = (float*)smem;             // 256*33*4 = 33792 B, overlaps dead kFrag+pS
    __syncthreads();
    #pragma unroll
    for (int d = 0; d < 2; ++d) {
        const int ct = wv + d * 4;
        #pragma unroll
        for (int r = 0; r < 16; ++r) {
            int c = ct * 32 + (r & 3) + 8 * (r >> 2) + 4 * (lane >> 5);
            scr[c * 33 + (lane & 31)] = accV[d][r] * linv;
        }
    }
    __syncthreads();
    {
        float* og = out + ((size_t)b * NC + tid) * NL + i0;
        #pragma unroll
        for (int g = 0; g < 8; ++g) {
            float4 o;
            o.x = scr[tid * 33 + g * 4 + 0];
            o.y = scr[tid * 33 + g * 4 + 1];
            o.z = scr[tid * 33 + g * 4 + 2];
            o.w = scr[tid * 33 + g * 4 + 3];
            *(float4*)(og + g * 4) = o;
        }
    }
    __syncthreads();
    #pragma unroll
    for (int d = 0; d < 2; ++d) {
        const int ct = wv + d * 4;
        #pragma unroll
        for (int r = 0; r < 16; ++r) {
            int c = ct * 32 + (r & 3) + 8 * (r >> 2) + 4 * (lane >> 5);
            scr[c * 33 + (lane & 31)] = accSD[d][r] * linv;
        }
    }
    __syncthreads();
    {
        float* og = out + (size_t)NB * NC * NL + ((size_t)b * NC + tid) * NL + i0;
        #pragma unroll
        for (int g = 0; g < 8; ++g) {
            float4 o;
            o.x = scr[tid * 33 + g * 4 + 0];
            o.y = scr[tid * 33 + g * 4 + 1];
            o.z = scr[tid * 33 + g * 4 + 2];
            o.w = scr[tid * 33 + g * 4 + 3];
            *(float4*)(og + g * 4) = o;
        }
    }
}

extern "C" void kernel_launch(void* const* d_in, const int* in_sizes, int n_in,
                              void* d_out, int out_size, void* d_ws, size_t ws_size,
                              hipStream_t stream)
{
    (void)in_sizes; (void)n_in; (void)d_ws; (void)ws_size; (void)out_size;
    const float* q  = (const float*)d_in[0];
    const float* k  = (const float*)d_in[1];
    const float* v  = (const float*)d_in[2];
    const float* s  = (const float*)d_in[3];
    const float* bt = (const float*)d_in[4];
    const int*   ri = (const int*)d_in[5];
    att_mfma<<<dim3(NB * (NL / MI)), dim3(256), 0, stream>>>(
        q, k, v, s, bt, ri, (float*)d_out);
}

// Round 4
// 422.772 us; speedup vs baseline: 3.6064x; 1.3329x over previous
//
#include <hip/hip_runtime.h>

typedef _Float16 half8 __attribute__((ext_vector_type(8)));
typedef _Float16 half4 __attribute__((ext_vector_type(4)));
typedef float    floatx16 __attribute__((ext_vector_type(16)));

constexpr int NB = 32, NC = 256, NL = 1024, MI = 32, BJ = 32;
constexpr int NIT = NL / BJ;   // 32

// LDS byte offsets (total 60032 < 64 KB static)
constexpr int OFF_K    = 0;        // kF  f16 [16 ks][64 ls][8 t] = 16384
constexpr int OFF_V    = 16384;    // vF  f16 [8 ct][2 ksj][64 ls][8 t] = 16384
constexpr int OFF_S    = 32768;    // sF  same = 16384
constexpr int OFF_PS   = 49152;    // pS  f32 [2 kh][32 i][33] = 8448
constexpr int PSP      = 33;
constexpr int OFF_PB   = 57600;    // pB  f16 [2 ksj][64 ls][8 t] = 2048
constexpr int OFF_ROWS = 59648;    // m/l/a rows 3*32*4 = 384
constexpr int SMEM_B   = 60032;

// K staging: coalesced global reads (lanes sweep j), conflict-free b128 frag writes.
// frag: B[k=c][n=j]: granule g=(ks,ls), j=ls&31, c=ks*16+(ls>>5)*8+t
__device__ __forceinline__ void stage_k(_Float16* kF, const float* kb, int tid) {
    #pragma unroll
    for (int r = 0; r < 4; ++r) {
        const int g = tid + r * 256, ks = g >> 6, ls = g & 63;
        const float* src = kb + (size_t)(ks * 16 + (ls >> 5) * 8) * NL + (ls & 31);
        half8 h;
        #pragma unroll
        for (int t = 0; t < 8; ++t) h[t] = (_Float16)src[(size_t)t * NL];
        *(half8*)(kF + g * 8) = h;
    }
}

// v/std staging: coalesced global reads (4 lanes per c-row), b128 frag writes.
// frag: A[m=c][k=j]: granule (ct,ksj,ls), m=ls&31 (=c&31), j=ksj*16+(ls>>5)*8+t
__device__ __forceinline__ void stage_a(_Float16* dst, const float* base, int tid) {
    #pragma unroll
    for (int r = 0; r < 4; ++r) {
        const int c = (tid >> 2) + r * 64, jc = tid & 3;
        const float* src = base + (size_t)c * NL + jc * 8;
        float4 a = *(const float4*)src;
        float4 b = *(const float4*)(src + 4);
        half8 h;
        h[0] = (_Float16)a.x; h[1] = (_Float16)a.y; h[2] = (_Float16)a.z; h[3] = (_Float16)a.w;
        h[4] = (_Float16)b.x; h[5] = (_Float16)b.y; h[6] = (_Float16)b.z; h[7] = (_Float16)b.w;
        const int gr = ((c >> 5) * 2 + (jc >> 1)) * 64 + (jc & 1) * 32 + (c & 31);
        *(half8*)(dst + gr * 8) = h;
    }
}

__global__ __launch_bounds__(256, 2)
void att_mfma2(const float* __restrict__ q,
               const float* __restrict__ kk,
               const float* __restrict__ v,
               const float* __restrict__ sd,
               const float* __restrict__ bt,
               const int* __restrict__ ri,
               float* __restrict__ out)
{
    __shared__ __align__(16) char smem[SMEM_B];
    _Float16* kF   = (_Float16*)(smem + OFF_K);
    _Float16* vF   = (_Float16*)(smem + OFF_V);
    _Float16* sF   = (_Float16*)(smem + OFF_S);
    float*    pS   = (float*)(smem + OFF_PS);
    _Float16* pB   = (_Float16*)(smem + OFF_PB);
    float*    mrow = (float*)(smem + OFF_ROWS);
    float*    lrow = mrow + 32;
    float*    arow = mrow + 64;

    const int tid  = threadIdx.x;
    const int lane = tid & 63;
    const int wv   = tid >> 6;

    // XCD-locality swizzle: one batch's 32 i-blocks cluster on one XCD.
    const int bid = blockIdx.x;
    const int b   = (bid & 7) + ((bid >> 8) << 3);
    const int ib  = (bid >> 3) & 31;
    const int i0  = ib * MI;

    const float* kbase = kk + (size_t)b * NC * NL;
    const float* vbase = v  + (size_t)b * NC * NL;
    const float* sbase = sd + (size_t)b * NC * NL;

    // ---- Q A-fragments (hi/lo fp16), waves 0,1 only: kh = wv, ks = wv*8+kk2 ----
    half8 qhi[8], qlo[8];
    if (wv < 2) {
        const float* qb = q + (size_t)b * NC * NL + i0 + (lane & 31);
        #pragma unroll
        for (int kk2 = 0; kk2 < 8; ++kk2) {
            const int c0 = (wv * 8 + kk2) * 16 + (lane >> 5) * 8;
            #pragma unroll
            for (int t = 0; t < 8; ++t) {
                float x = qb[(size_t)(c0 + t) * NL];
                _Float16 h = (_Float16)x;
                qhi[kk2][t] = h;
                qlo[kk2][t] = (_Float16)(x - (float)h);
            }
        }
    }
    if (tid < 32) { mrow[tid] = -1e30f; lrow[tid] = 0.0f; arow[tid] = 1.0f; }

    floatx16 aV[2], aS[2];
    #pragma unroll
    for (int d = 0; d < 2; ++d)
        #pragma unroll
        for (int r = 0; r < 16; ++r) { aV[d][r] = 0.f; aS[d][r] = 0.f; }

    stage_k(kF, kbase, tid);       // kF(0)
    __syncthreads();

    for (int it = 0; it < NIT; ++it) {
        const int j0 = it * BJ;

        // ---- PV(it-1): all waves, 2 c-tiles each ----
        if (it > 0) {
            const float al = arow[lane & 31];
            #pragma unroll
            for (int d = 0; d < 2; ++d)
                #pragma unroll
                for (int r = 0; r < 16; ++r) { aV[d][r] *= al; aS[d][r] *= al; }
            half8 pb0 = *(const half8*)(pB + lane * 8);
            half8 pb1 = *(const half8*)(pB + (64 + lane) * 8);
            #pragma unroll
            for (int d = 0; d < 2; ++d) {
                const int ct = wv * 2 + d;
                const int g0 = (ct * 2) * 64 * 8 + lane * 8;
                half8 a0 = *(const half8*)(vF + g0);
                half8 a1 = *(const half8*)(vF + g0 + 512);
                aV[d] = __builtin_amdgcn_mfma_f32_32x32x16_f16(a0, pb0, aV[d], 0, 0, 0);
                aV[d] = __builtin_amdgcn_mfma_f32_32x32x16_f16(a1, pb1, aV[d], 0, 0, 0);
                half8 b0 = *(const half8*)(sF + g0);
                half8 b1 = *(const half8*)(sF + g0 + 512);
                aS[d] = __builtin_amdgcn_mfma_f32_32x32x16_f16(b0, pb0, aS[d], 0, 0, 0);
                aS[d] = __builtin_amdgcn_mfma_f32_32x32x16_f16(b1, pb1, aS[d], 0, 0, 0);
            }
        }

        // ---- scores(it): waves 0,1 (kh = wv) ----
        if (wv < 2) {
            floatx16 S;
            #pragma unroll
            for (int r = 0; r < 16; ++r) S[r] = 0.f;
            #pragma unroll
            for (int kk2 = 0; kk2 < 8; ++kk2) {
                const int ks = wv * 8 + kk2;
                half8 bf = *(const half8*)(kF + (ks * 64 + lane) * 8);
                S = __builtin_amdgcn_mfma_f32_32x32x16_f16(qhi[kk2], bf, S, 0, 0, 0);
                S = __builtin_amdgcn_mfma_f32_32x32x16_f16(qlo[kk2], bf, S, 0, 0, 0);
            }
            float* ps = pS + wv * 32 * PSP + (lane & 31);
            #pragma unroll
            for (int r = 0; r < 16; ++r) {
                int row = (r & 3) + 8 * (r >> 2) + 4 * (lane >> 5);
                ps[row * PSP] = S[r];
            }
        }
        __syncthreads();   // B1: pS ready; kF/vF/sF old reads done

        // ---- stage kF(it+1), vF/sF(it) ----
        if (it + 1 < NIT) stage_k(kF, kbase + j0 + BJ, tid);
        stage_a(vF, vbase + j0, tid);
        stage_a(sF, sbase + j0, tid);

        // ---- softmax(it): thread (i = tid>>3, s = tid&7) owns 4 cols ----
        {
            const int i = tid >> 3, s = tid & 7;
            const int4 r4 = *(const int4*)(ri + (size_t)(i0 + i) * NL + j0 + s * 4);
            const float* ps0 = pS + i * PSP + s * 4;
            float sc[4];
            sc[0] = ps0[0] + ps0[32 * PSP + 0] + bt[r4.x];
            sc[1] = ps0[1] + ps0[32 * PSP + 1] + bt[r4.y];
            sc[2] = ps0[2] + ps0[32 * PSP + 2] + bt[r4.z];
            sc[3] = ps0[3] + ps0[32 * PSP + 3] + bt[r4.w];
            float lm = fmaxf(fmaxf(sc[0], sc[1]), fmaxf(sc[2], sc[3]));
            lm = fmaxf(lm, __shfl_xor(lm, 1));
            lm = fmaxf(lm, __shfl_xor(lm, 2));
            lm = fmaxf(lm, __shfl_xor(lm, 4));
            const float mo = mrow[i];
            const float mn = fmaxf(lm, mo);
            float sum = 0.f;
            half4 ph;
            #pragma unroll
            for (int x = 0; x < 4; ++x) {
                float e = __expf(sc[x] - mn);
                sum += e;
                ph[x] = (_Float16)e;
            }
            sum += __shfl_xor(sum, 1);
            sum += __shfl_xor(sum, 2);
            sum += __shfl_xor(sum, 4);
            // pB frag: B[k=j][n=i], j = 4s..4s+3 -> ksj=s>>2, half=(s>>1)&1, t0=(s&1)*4
            *(half4*)(pB + (((s >> 2) * 64) + ((s >> 1) & 1) * 32 + i) * 8 + (s & 1) * 4) = ph;
            if (s == 0) {
                float al = __expf(mo - mn);
                arow[i] = al;
                lrow[i] = lrow[i] * al + sum;
                mrow[i] = mn;
            }
        }
        __syncthreads();   // B2: pB/rows/kF(it+1)/vF/sF(it) ready
    }

    // ---- drain PV(NIT-1) ----
    {
        const float al = arow[lane & 31];
        #pragma unroll
        for (int d = 0; d < 2; ++d)
            #pragma unroll
            for (int r = 0; r < 16; ++r) { aV[d][r] *= al; aS[d][r] *= al; }
        half8 pb0 = *(const half8*)(pB + lane * 8);
        half8 pb1 = *(const half8*)(pB + (64 + lane) * 8);
        #pragma unroll
        for (int d = 0; d < 2; ++d) {
            const int ct = wv * 2 + d;
            const int g0 = (ct * 2) * 64 * 8 + lane * 8;
            half8 a0 = *(const half8*)(vF + g0);
            half8 a1 = *(const half8*)(vF + g0 + 512);
            aV[d] = __builtin_amdgcn_mfma_f32_32x32x16_f16(a0, pb0, aV[d], 0, 0, 0);
            aV[d] = __builtin_amdgcn_mfma_f32_32x32x16_f16(a1, pb1, aV[d], 0, 0, 0);
            half8 b0 = *(const half8*)(sF + g0);
            half8 b1 = *(const half8*)(sF + g0 + 512);
            aS[d] = __builtin_amdgcn_mfma_f32_32x32x16_f16(b0, pb0, aS[d], 0, 0, 0);
            aS[d] = __builtin_amdgcn_mfma_f32_32x32x16_f16(b1, pb1, aS[d], 0, 0, 0);
        }
    }

    // ---- epilogue: normalize, LDS transpose (scr overlaps dead kF/vF), coalesced store ----
    const float linv = 1.0f / lrow[lane & 31];
    float* scr = (float*)smem;   // 256*33*4 = 33792 B
    __syncthreads();
    #pragma unroll
    for (int d = 0; d < 2; ++d) {
        const int ct = wv * 2 + d;
        #pragma unroll
        for (int r = 0; r < 16; ++r) {
            int c = ct * 32 + (r & 3) + 8 * (r >> 2) + 4 * (lane >> 5);
            scr[c * 33 + (lane & 31)] = aV[d][r] * linv;
        }
    }
    __syncthreads();
    {
        float* og = out + ((size_t)b * NC + tid) * NL + i0;
        #pragma unroll
        for (int g = 0; g < 8; ++g) {
            float4 o;
            o.x = scr[tid * 33 + g * 4 + 0];
            o.y = scr[tid * 33 + g * 4 + 1];
            o.z = scr[tid * 33 + g * 4 + 2];
            o.w = scr[tid * 33 + g * 4 + 3];
            *(float4*)(og + g * 4) = o;
        }
    }
    __syncthreads();
    #pragma unroll
    for (int d = 0; d < 2; ++d) {
        const int ct = wv * 2 + d;
        #pragma unroll
        for (int r = 0; r < 16; ++r) {
            int c = ct * 32 + (r & 3) + 8 * (r >> 2) + 4 * (lane >> 5);
            scr[c * 33 + (lane & 31)] = aS[d][r] * linv;
        }
    }
    __syncthreads();
    {
        float* og = out + (size_t)NB * NC * NL + ((size_t)b * NC + tid) * NL + i0;
        #pragma unroll
        for (int g = 0; g < 8; ++g) {
            float4 o;
            o.x = scr[tid * 33 + g * 4 + 0];
            o.y = scr[tid * 33 + g * 4 + 1];
            o.z = scr[tid * 33 + g * 4 + 2];
            o.w = scr[tid * 33 + g * 4 + 3];
            *(float4*)(og + g * 4) = o;
        }
    }
}

extern "C" void kernel_launch(void* const* d_in, const int* in_sizes, int n_in,
                              void* d_out, int out_size, void* d_ws, size_t ws_size,
                              hipStream_t stream)
{
    (void)in_sizes; (void)n_in; (void)d_ws; (void)ws_size; (void)out_size;
    const float* q  = (const float*)d_in[0];
    const float* k  = (const float*)d_in[1];
    const float* v  = (const float*)d_in[2];
    const float* s  = (const float*)d_in[3];
    const float* bt = (const float*)d_in[4];
    const int*   ri = (const int*)d_in[5];
    att_mfma2<<<dim3(NB * (NL / MI)), dim3(256), 0, stream>>>(
        q, k, v, s, bt, ri, (float*)d_out);
}